// Round 1
// baseline (2592.113 us; speedup 1.0000x reference)
//
#include <hip/hip_runtime.h>

// ---------------- types / helpers ----------------
typedef __attribute__((ext_vector_type(8))) short bf16x8;
typedef __attribute__((ext_vector_type(4))) float f32x4;

#define L_LAYERS 6
#define T_SEQ 1024
#define D_MODEL 1024
#define N_HEAD 16
#define HS 64
#define FF_DIM 4096
#define VOCAB 32000
#define BT_ROWS 4096           // B*T
#define ATTN_SCALE 0.03125f    // D**-0.5 (reference scales by D, not HS)

__device__ __forceinline__ ushort f2bf(float f) {
  unsigned u = __builtin_bit_cast(unsigned, f);
  unsigned r = (u + 0x7fffu + ((u >> 16) & 1u)) >> 16;
  return (ushort)r;
}
__device__ __forceinline__ float waveRedSum(float v) {
#pragma unroll
  for (int off = 32; off; off >>= 1) v += __shfl_xor(v, off);
  return v;
}
__device__ __forceinline__ float waveRedMax(float v) {
#pragma unroll
  for (int off = 32; off; off >>= 1) v = fmaxf(v, __shfl_xor(v, off));
  return v;
}

// ---------------- embedding: x[m][d] = tok[idx[m]][d] + pos[m%T][d] ----------------
__global__ __launch_bounds__(256) void embed_kernel(const int* __restrict__ idx,
                                                    const float* __restrict__ tok,
                                                    const float* __restrict__ pos,
                                                    float* __restrict__ x) {
  int row = blockIdx.x;           // 4096 rows
  int tid = threadIdx.x;          // 256 threads * float4 = 1024
  int t = row & (T_SEQ - 1);
  int id = idx[row];
  float4 tv = ((const float4*)(tok + (size_t)id * D_MODEL))[tid];
  float4 pv = ((const float4*)(pos + (size_t)t * D_MODEL))[tid];
  tv.x += pv.x; tv.y += pv.y; tv.z += pv.z; tv.w += pv.w;
  ((float4*)(x + (size_t)row * D_MODEL))[tid] = tv;
}

// ---------------- LayerNorm f32 -> bf16 ----------------
__global__ __launch_bounds__(256) void ln_kernel(const float* __restrict__ x,
                                                 const float* __restrict__ g,
                                                 const float* __restrict__ b,
                                                 ushort* __restrict__ out) {
  int row = blockIdx.x;
  int tid = threadIdx.x;
  __shared__ float red[4];
  float4 xv = ((const float4*)(x + (size_t)row * D_MODEL))[tid];
  float s = xv.x + xv.y + xv.z + xv.w;
  s = waveRedSum(s);
  if ((tid & 63) == 0) red[tid >> 6] = s;
  __syncthreads();
  float mean = (red[0] + red[1] + red[2] + red[3]) * (1.0f / D_MODEL);
  __syncthreads();
  float d0 = xv.x - mean, d1 = xv.y - mean, d2 = xv.z - mean, d3 = xv.w - mean;
  float v = d0 * d0 + d1 * d1 + d2 * d2 + d3 * d3;
  v = waveRedSum(v);
  if ((tid & 63) == 0) red[tid >> 6] = v;
  __syncthreads();
  float var = (red[0] + red[1] + red[2] + red[3]) * (1.0f / D_MODEL);
  float rstd = rsqrtf(var + 1e-5f);
  float4 gv = ((const float4*)g)[tid];
  float4 bv = ((const float4*)b)[tid];
  ushort4 o;
  o.x = f2bf(d0 * rstd * gv.x + bv.x);
  o.y = f2bf(d1 * rstd * gv.y + bv.y);
  o.z = f2bf(d2 * rstd * gv.z + bv.z);
  o.w = f2bf(d3 * rstd * gv.w + bv.w);
  ((ushort4*)(out + (size_t)row * D_MODEL))[tid] = o;
}

// ---------------- weight convert+transpose: W f32 [Kd][Nd-slice] -> WT bf16 [n][Kd] ----------------
// grid: (nTiles, kTiles), 64x64 tiles
__global__ __launch_bounds__(256) void wconv_kernel(const float* __restrict__ W,
                                                    ushort* __restrict__ WT,
                                                    int Kd, int Nd) {
  __shared__ ushort tile[64][72];
  int n0 = blockIdx.x * 64, k0 = blockIdx.y * 64;
  int tid = threadIdx.x;
#pragma unroll
  for (int i = 0; i < 4; i++) {
    int c = tid + i * 256;          // 64 rows x 16 float4-chunks
    int row = c >> 4, cc = c & 15;
    float4 wv = *(const float4*)&W[(size_t)(k0 + row) * Nd + n0 + cc * 4];
    tile[row][cc * 4 + 0] = f2bf(wv.x);
    tile[row][cc * 4 + 1] = f2bf(wv.y);
    tile[row][cc * 4 + 2] = f2bf(wv.z);
    tile[row][cc * 4 + 3] = f2bf(wv.w);
  }
  __syncthreads();
#pragma unroll
  for (int i = 0; i < 2; i++) {
    int c = tid + i * 256;          // 64 n-rows x 8 chunks of 8 bf16
    int n = c >> 3, kc = c & 7;
    __align__(16) ushort tmp[8];
#pragma unroll
    for (int j = 0; j < 8; j++) tmp[j] = tile[kc * 8 + j][n];
    *(int4*)&WT[(size_t)(n0 + n) * Kd + k0 + kc * 8] = *(const int4*)tmp;
  }
}

// ---------------- bf16 transpose: v [BH][T][HS] -> vT [BH][HS][T] ----------------
__global__ __launch_bounds__(256) void vtrans_kernel(const ushort* __restrict__ v,
                                                     ushort* __restrict__ vT) {
  __shared__ ushort tile[64][72];
  int bh = blockIdx.y;
  int t0 = blockIdx.x * 64;
  int tid = threadIdx.x;
#pragma unroll
  for (int i = 0; i < 2; i++) {
    int c = tid + i * 256;          // 64 t-rows x 8 chunks (8 u16)
    int row = c >> 3, cc = c & 7;
    *(int4*)&tile[row][cc * 8] =
        *(const int4*)&v[((size_t)bh * T_SEQ + t0 + row) * HS + cc * 8];
  }
  __syncthreads();
#pragma unroll
  for (int i = 0; i < 2; i++) {
    int c = tid + i * 256;          // 64 hs-rows x 8 chunks
    int hs = c >> 3, tc = c & 7;
    __align__(16) ushort tmp[8];
#pragma unroll
    for (int j = 0; j < 8; j++) tmp[j] = tile[tc * 8 + j][hs];
    *(int4*)&vT[((size_t)bh * HS + hs) * T_SEQ + t0 + tc * 8] = *(const int4*)tmp;
  }
}

// ---------------- GEMM: C[M][N] = A[M][K](bf16) * BT[N][K](bf16)^T ----------------
// 128x128 tile, BK=64, 4 waves (2x2), 4x4 16x16x32 frags per wave.
// EPI 0: scatter to q/k/v [BH][T][HS] bf16
// EPI 1: outf[m*ldo+n] += acc + bias[n]          (residual f32)
// EPI 2: outb[m*ldo+n]  = bf16(relu(acc+bias))   (ff1)
// EPI 3: outf[m*ldo+n]  = acc + bias[n]          (head, f32)
template <int EPI>
__global__ __launch_bounds__(256) void gemm_kernel(const ushort* __restrict__ A,
                                                   const ushort* __restrict__ BT,
                                                   int K,
                                                   const float* __restrict__ bias,
                                                   float* __restrict__ outf,
                                                   ushort* __restrict__ outb,
                                                   ushort* __restrict__ outk,
                                                   ushort* __restrict__ outv,
                                                   int ldo) {
  __shared__ __align__(16) ushort Asm[128 * 72];
  __shared__ __align__(16) ushort Bsm[128 * 72];
  int tid = threadIdx.x;
  int lane = tid & 63, wave = tid >> 6;
  int wm = wave >> 1, wn = wave & 1;
  int a = lane & 15, gg = lane >> 4;
  int m0 = blockIdx.y * 128, n0 = blockIdx.x * 128;
  f32x4 acc[4][4] = {};

  for (int k0 = 0; k0 < K; k0 += 64) {
    __syncthreads();
#pragma unroll
    for (int i = 0; i < 4; i++) {
      int c = tid + i * 256;        // 128 rows x 8 chunks of 8 bf16
      int row = c >> 3, cc = c & 7;
      *(int4*)&Asm[row * 72 + cc * 8] =
          *(const int4*)&A[(size_t)(m0 + row) * K + k0 + cc * 8];
      *(int4*)&Bsm[row * 72 + cc * 8] =
          *(const int4*)&BT[(size_t)(n0 + row) * K + k0 + cc * 8];
    }
    __syncthreads();
#pragma unroll
    for (int s = 0; s < 2; s++) {
      bf16x8 af[4], bfr[4];
#pragma unroll
      for (int i = 0; i < 4; i++)
        af[i] = *(const bf16x8*)&Asm[(wm * 64 + i * 16 + a) * 72 + s * 32 + gg * 8];
#pragma unroll
      for (int j = 0; j < 4; j++)
        bfr[j] = *(const bf16x8*)&Bsm[(wn * 64 + j * 16 + a) * 72 + s * 32 + gg * 8];
#pragma unroll
      for (int i = 0; i < 4; i++)
#pragma unroll
        for (int j = 0; j < 4; j++)
          acc[i][j] = __builtin_amdgcn_mfma_f32_16x16x32_bf16(af[i], bfr[j], acc[i][j], 0, 0, 0);
    }
  }

#pragma unroll
  for (int i = 0; i < 4; i++) {
#pragma unroll
    for (int j = 0; j < 4; j++) {
#pragma unroll
      for (int r = 0; r < 4; r++) {
        int mrow = m0 + wm * 64 + i * 16 + gg * 4 + r;
        int ncol = n0 + wn * 64 + j * 16 + a;
        float v = acc[i][j][r];
        if (EPI == 0) {
          int which = ncol >> 10;
          int n1 = ncol & 1023;
          int h = n1 >> 6, sidx = n1 & 63;
          int bb = mrow >> 10, tt = mrow & 1023;
          ushort* dst = (which == 0) ? outb : (which == 1) ? outk : outv;
          dst[(((size_t)(bb * N_HEAD + h)) * T_SEQ + tt) * HS + sidx] = f2bf(v);
        } else if (EPI == 1) {
          outf[(size_t)mrow * ldo + ncol] += v + bias[ncol];
        } else if (EPI == 2) {
          float t = v + bias[ncol];
          outb[(size_t)mrow * ldo + ncol] = f2bf(t > 0.0f ? t : 0.0f);
        } else {
          outf[(size_t)mrow * ldo + ncol] = v + bias[ncol];
        }
      }
    }
  }
}

// ---------------- fused causal flash attention ----------------
// grid (16 qtiles, 64 bh), 4 waves, each wave owns 16 q rows.
// Swapped QK^T: st = mfma(Kfrag, Qfrag) -> S^T[u][q], q = lane&15 (lane-local softmax).
__global__ __launch_bounds__(256) void attn_kernel(const ushort* __restrict__ q,
                                                   const ushort* __restrict__ k,
                                                   const ushort* __restrict__ vT,
                                                   ushort* __restrict__ o) {
  __shared__ __align__(16) ushort Ksm[64 * 72];
  __shared__ __align__(16) ushort Vsm[64 * 72];   // V^T tile: [hs][u]
  __shared__ __align__(16) ushort Psm[4][16 * 72];
  int tid = threadIdx.x;
  int lane = tid & 63, w = tid >> 6;
  int a = lane & 15, gg = lane >> 4;
  int qt = blockIdx.x, bh = blockIdx.y;
  int qrow_b = qt * 64 + w * 16;
  int qmy = qrow_b + a;

  bf16x8 qf[2];
  const ushort* qbase = q + ((size_t)bh * T_SEQ + qmy) * HS;
  qf[0] = *(const bf16x8*)&qbase[gg * 8];
  qf[1] = *(const bf16x8*)&qbase[32 + gg * 8];

  float m_run = -__builtin_inff();
  float l_run = 0.0f;
  f32x4 oacc[4] = {};
  int nkt = qt + 1;

  for (int kt = 0; kt < nkt; kt++) {
    int k0 = kt * 64;
    __syncthreads();
#pragma unroll
    for (int i = 0; i < 2; i++) {
      int c = tid + i * 256;
      int row = c >> 3, cc = c & 7;
      *(int4*)&Ksm[row * 72 + cc * 8] =
          *(const int4*)&k[((size_t)bh * T_SEQ + k0 + row) * HS + cc * 8];
      *(int4*)&Vsm[row * 72 + cc * 8] =
          *(const int4*)&vT[((size_t)bh * HS + row) * T_SEQ + k0 + cc * 8];
    }
    __syncthreads();

    f32x4 st[4] = {};
#pragma unroll
    for (int ku = 0; ku < 4; ku++) {
#pragma unroll
      for (int s = 0; s < 2; s++) {
        bf16x8 kf = *(const bf16x8*)&Ksm[(ku * 16 + a) * 72 + s * 32 + gg * 8];
        st[ku] = __builtin_amdgcn_mfma_f32_16x16x32_bf16(kf, qf[s], st[ku], 0, 0, 0);
      }
    }

    float pv[16];
    float pm = -__builtin_inff();
#pragma unroll
    for (int ku = 0; ku < 4; ku++) {
#pragma unroll
      for (int r = 0; r < 4; r++) {
        int u = k0 + ku * 16 + gg * 4 + r;
        float val = (u <= qmy) ? st[ku][r] * ATTN_SCALE : -__builtin_inff();
        pv[ku * 4 + r] = val;
        pm = fmaxf(pm, val);
      }
    }
    pm = fmaxf(pm, __shfl_xor(pm, 16));
    pm = fmaxf(pm, __shfl_xor(pm, 32));
    float m_new = fmaxf(m_run, pm);
    float cfac = expf(m_run - m_new);   // exp(-inf)=0 on first tile
    float tsum = 0.0f;
#pragma unroll
    for (int xi = 0; xi < 16; xi++) {
      float p = expf(pv[xi] - m_new);
      pv[xi] = p;
      tsum += p;
    }
    tsum += __shfl_xor(tsum, 16);
    tsum += __shfl_xor(tsum, 32);
    l_run = l_run * cfac + tsum;
    m_run = m_new;

    // write P (bf16) into this wave's LDS region: P[q=a][u]
    ushort* P = (ushort*)&Psm[w][0];
    asm volatile("s_waitcnt lgkmcnt(0)" ::: "memory");
#pragma unroll
    for (int ku = 0; ku < 4; ku++) {
      ushort4 pw;
      pw.x = f2bf(pv[ku * 4 + 0]);
      pw.y = f2bf(pv[ku * 4 + 1]);
      pw.z = f2bf(pv[ku * 4 + 2]);
      pw.w = f2bf(pv[ku * 4 + 3]);
      *(ushort4*)&P[a * 72 + ku * 16 + gg * 4] = pw;
    }
    // rescale O by per-row correction
#pragma unroll
    for (int r = 0; r < 4; r++) {
      float cr = __shfl(cfac, gg * 4 + r);
#pragma unroll
      for (int nb = 0; nb < 4; nb++) oacc[nb][r] *= cr;
    }
    asm volatile("s_waitcnt lgkmcnt(0)" ::: "memory");
    // PV: O[q][hs] += P[q][u] * V[u][hs]
#pragma unroll
    for (int kb = 0; kb < 2; kb++) {
      bf16x8 pa = *(const bf16x8*)&P[a * 72 + kb * 32 + gg * 8];
#pragma unroll
      for (int nb = 0; nb < 4; nb++) {
        bf16x8 vb = *(const bf16x8*)&Vsm[(nb * 16 + a) * 72 + kb * 32 + gg * 8];
        oacc[nb] = __builtin_amdgcn_mfma_f32_16x16x32_bf16(pa, vb, oacc[nb], 0, 0, 0);
      }
    }
  }

  float linv = 1.0f / l_run;
  int bb = bh >> 4, hh = bh & 15;
#pragma unroll
  for (int r = 0; r < 4; r++) {
    float li = __shfl(linv, gg * 4 + r);
    int qr = qrow_b + gg * 4 + r;
#pragma unroll
    for (int nb = 0; nb < 4; nb++) {
      o[((size_t)(bb * T_SEQ + qr)) * D_MODEL + hh * HS + nb * 16 + a] =
          f2bf(oacc[nb][r] * li);
    }
  }
}

// ---------------- loss ----------------
__global__ __launch_bounds__(256) void loss_row_kernel(const float* __restrict__ logits,
                                                       const int* __restrict__ tgt,
                                                       float* __restrict__ row_loss) {
  int row = blockIdx.x, tid = threadIdx.x;
  __shared__ float red[4];
  const float4* l4 = (const float4*)(logits + (size_t)row * VOCAB);
  float mx = -__builtin_inff();
  for (int i = tid; i < VOCAB / 4; i += 256) {
    float4 v = l4[i];
    mx = fmaxf(fmaxf(mx, fmaxf(v.x, v.y)), fmaxf(v.z, v.w));
  }
  mx = waveRedMax(mx);
  if ((tid & 63) == 0) red[tid >> 6] = mx;
  __syncthreads();
  mx = fmaxf(fmaxf(red[0], red[1]), fmaxf(red[2], red[3]));
  __syncthreads();
  float s = 0.0f;
  for (int i = tid; i < VOCAB / 4; i += 256) {
    float4 v = l4[i];
    s += expf(v.x - mx) + expf(v.y - mx) + expf(v.z - mx) + expf(v.w - mx);
  }
  s = waveRedSum(s);
  if ((tid & 63) == 0) red[tid >> 6] = s;
  __syncthreads();
  if (tid == 0) {
    float tot = red[0] + red[1] + red[2] + red[3];
    row_loss[row] = mx + logf(tot) - logits[(size_t)row * VOCAB + tgt[row]];
  }
}

__global__ __launch_bounds__(256) void loss_final_kernel(const float* __restrict__ row_loss,
                                                         float* __restrict__ out) {
  int tid = threadIdx.x;
  __shared__ float red[4];
  float s = 0.0f;
  for (int i = tid; i < BT_ROWS; i += 256) s += row_loss[i];
  s = waveRedSum(s);
  if ((tid & 63) == 0) red[tid >> 6] = s;
  __syncthreads();
  if (tid == 0) out[0] = (red[0] + red[1] + red[2] + red[3]) * (1.0f / BT_ROWS);
}

// ---------------- orchestration ----------------
extern "C" void kernel_launch(void* const* d_in, const int* in_sizes, int n_in,
                              void* d_out, int out_size, void* d_ws, size_t ws_size,
                              hipStream_t stream) {
  const int* idx = (const int*)d_in[0];
  const int* tgt = (const int*)d_in[1];
  const float* tok_emb = (const float*)d_in[2];
  const float* pos_emb = (const float*)d_in[3];
  const float* Wq = (const float*)d_in[4];
  const float* Wk = (const float*)d_in[5];
  const float* Wv = (const float*)d_in[6];
  const float* proj_w = (const float*)d_in[7];
  const float* proj_b = (const float*)d_in[8];
  const float* ln1_g = (const float*)d_in[9];
  const float* ln1_b = (const float*)d_in[10];
  const float* ln2_g = (const float*)d_in[11];
  const float* ln2_b = (const float*)d_in[12];
  const float* ff_w1 = (const float*)d_in[13];
  const float* ff_b1 = (const float*)d_in[14];
  const float* ff_w2 = (const float*)d_in[15];
  const float* ff_b2 = (const float*)d_in[16];
  const float* lnf_g = (const float*)d_in[17];
  const float* lnf_b = (const float*)d_in[18];
  const float* head_w = (const float*)d_in[19];
  const float* head_b = (const float*)d_in[20];

  char* ws = (char*)d_ws;
  size_t off = 0;
  float* x = (float*)(ws + off); off += (size_t)BT_ROWS * D_MODEL * 4;        // 16.78MB
  ushort* h = (ushort*)(ws + off); off += (size_t)BT_ROWS * D_MODEL * 2;      // 8.39MB
  ushort* qb = (ushort*)(ws + off); off += (size_t)BT_ROWS * D_MODEL * 2;
  ushort* kb = (ushort*)(ws + off); off += (size_t)BT_ROWS * D_MODEL * 2;
  ushort* vb = (ushort*)(ws + off); off += (size_t)BT_ROWS * D_MODEL * 2;
  ushort* vTb = (ushort*)(ws + off); off += (size_t)BT_ROWS * D_MODEL * 2;
  ushort* ob = (ushort*)(ws + off); off += (size_t)BT_ROWS * D_MODEL * 2;
  ushort* ffb = (ushort*)(ws + off); off += (size_t)BT_ROWS * FF_DIM * 2;     // 33.55MB
  ushort* wqkvT = (ushort*)(ws + off); off += (size_t)3 * D_MODEL * D_MODEL * 2; // 6.29MB
  ushort* wprojT = (ushort*)(ws + off); off += (size_t)D_MODEL * D_MODEL * 2;
  ushort* wff1T = (ushort*)(ws + off); off += (size_t)FF_DIM * D_MODEL * 2;
  ushort* wff2T = (ushort*)(ws + off); off += (size_t)D_MODEL * FF_DIM * 2;
  float* row_loss = (float*)(ws + off); off += (size_t)BT_ROWS * 4;
  ushort* headT = wqkvT;  // head chunks reuse layer-weight region (13.1MB <= 25.2MB)

  float* logits = (float*)d_out;

  embed_kernel<<<BT_ROWS, 256, 0, stream>>>(idx, tok_emb, pos_emb, x);

  for (int l = 0; l < L_LAYERS; l++) {
    size_t wo = (size_t)l * D_MODEL * D_MODEL;
    size_t fo = (size_t)l * D_MODEL * FF_DIM;
    // weight conversion (f32 [K][N] -> bf16 [N][K])
    wconv_kernel<<<dim3(16, 16), 256, 0, stream>>>(Wq + wo, wqkvT + 0 * D_MODEL * D_MODEL, D_MODEL, D_MODEL);
    wconv_kernel<<<dim3(16, 16), 256, 0, stream>>>(Wk + wo, wqkvT + 1 * D_MODEL * D_MODEL, D_MODEL, D_MODEL);
    wconv_kernel<<<dim3(16, 16), 256, 0, stream>>>(Wv + wo, wqkvT + 2 * D_MODEL * D_MODEL, D_MODEL, D_MODEL);
    wconv_kernel<<<dim3(16, 16), 256, 0, stream>>>(proj_w + wo, wprojT, D_MODEL, D_MODEL);
    wconv_kernel<<<dim3(64, 16), 256, 0, stream>>>(ff_w1 + fo, wff1T, D_MODEL, FF_DIM);
    wconv_kernel<<<dim3(16, 64), 256, 0, stream>>>(ff_w2 + fo, wff2T, FF_DIM, D_MODEL);

    // LN1 -> h
    ln_kernel<<<BT_ROWS, 256, 0, stream>>>(x, ln1_g + l * D_MODEL, ln1_b + l * D_MODEL, h);
    // QKV gemm (N=3072), scatter into q/k/v [BH][T][HS]
    gemm_kernel<0><<<dim3(24, 32), 256, 0, stream>>>(h, wqkvT, D_MODEL, nullptr,
                                                     nullptr, qb, kb, vb, 0);
    // V transpose
    vtrans_kernel<<<dim3(16, 64), 256, 0, stream>>>(vb, vTb);
    // attention
    attn_kernel<<<dim3(16, 64), 256, 0, stream>>>(qb, kb, vTb, ob);
    // proj + residual into x
    gemm_kernel<1><<<dim3(8, 32), 256, 0, stream>>>(ob, wprojT, D_MODEL,
                                                    proj_b + l * D_MODEL, x,
                                                    nullptr, nullptr, nullptr, D_MODEL);
    // LN2 -> h
    ln_kernel<<<BT_ROWS, 256, 0, stream>>>(x, ln2_g + l * D_MODEL, ln2_b + l * D_MODEL, h);
    // FF1: relu -> ffb
    gemm_kernel<2><<<dim3(32, 32), 256, 0, stream>>>(h, wff1T, D_MODEL,
                                                     ff_b1 + (size_t)l * FF_DIM, nullptr,
                                                     ffb, nullptr, nullptr, FF_DIM);
    // FF2 + residual into x
    gemm_kernel<1><<<dim3(8, 32), 256, 0, stream>>>(ffb, wff2T, FF_DIM,
                                                    ff_b2 + l * D_MODEL, x,
                                                    nullptr, nullptr, nullptr, D_MODEL);
  }

  // final LN -> h
  ln_kernel<<<BT_ROWS, 256, 0, stream>>>(x, lnf_g, lnf_b, h);

  // head: 5 chunks of 6400 columns
  for (int c = 0; c < 5; c++) {
    wconv_kernel<<<dim3(100, 16), 256, 0, stream>>>(head_w + c * 6400, headT, D_MODEL, VOCAB);
    gemm_kernel<3><<<dim3(50, 32), 256, 0, stream>>>(h, headT, D_MODEL,
                                                     head_b + c * 6400,
                                                     logits + c * 6400,
                                                     nullptr, nullptr, nullptr, VOCAB);
  }

  // loss
  loss_row_kernel<<<BT_ROWS, 256, 0, stream>>>(logits, tgt, row_loss);
  loss_final_kernel<<<1, 256, 0, stream>>>(row_loss, logits + (size_t)BT_ROWS * VOCAB);
}